// Round 4
// baseline (271.522 us; speedup 1.0000x reference)
//
#include <hip/hip_runtime.h>
#include <stdint.h>

#define NDIM 512
#define HEADS 8
#define DHEAD 64
#define NSEQ 4096
#define BATCH 8
#define ROWS (BATCH * NSEQ)   // 32768
#define QKVN (3 * NDIM)       // 1536

typedef unsigned short ushort_t;
typedef __bf16 bf16x8 __attribute__((ext_vector_type(8)));
typedef float f32x4 __attribute__((ext_vector_type(4)));
typedef unsigned short u16x8 __attribute__((ext_vector_type(8)));
typedef unsigned short u16x4 __attribute__((ext_vector_type(4)));

__device__ __forceinline__ ushort_t f2bf(float f) {
  union { float f; uint32_t u; } v; v.f = f;
  uint32_t r = (v.u + 0x7FFFu + ((v.u >> 16) & 1u)) >> 16;
  return (ushort_t)r;
}
__device__ __forceinline__ float bf2f(ushort_t h) {
  union { uint32_t u; float f; } v; v.u = ((uint32_t)h) << 16;
  return v.f;
}

__device__ __forceinline__ void gload_lds16(const void* g, void* l) {
  __builtin_amdgcn_global_load_lds(
      (__attribute__((address_space(1))) void*)(g),
      (__attribute__((address_space(3))) void*)(l), 16, 0, 0);
}

// ---------------------------------------------------------------------------
// K1: fused prep. Grid layout (256 threads each):
//   [0,8192)       rmsnorm (4 rows/block) -> xn bf16
//   [8192,8704)    wqkT transpose: w_qkv cols 0..1023 -> wqkT[1024][512]
//   [8704,8960)    woutT transpose: w_out -> woutT[512][512]
//   [8960,9088)    wv cast: w_qkv cols 1024..1535 -> wv[512 c][512 hE] bf16
//   [9088,9600)    zero S f32 (8 MB)
// ---------------------------------------------------------------------------
__global__ __launch_bounds__(256) void prep_rms_k(const float* __restrict__ x,
                                                  const float* __restrict__ gamma,
                                                  ushort_t* __restrict__ xn,
                                                  const float* __restrict__ w_qkv,
                                                  const float* __restrict__ w_out,
                                                  ushort_t* __restrict__ wqkT,
                                                  ushort_t* __restrict__ woutT,
                                                  ushort_t* __restrict__ wv,
                                                  float* __restrict__ S) {
  __shared__ float tile[32][33];
  int bid = blockIdx.x;
  int t = threadIdx.x;
  if (bid < 8192) {
    int wave = t >> 6, lane = t & 63;
    size_t row = (size_t)bid * 4 + wave;
    const float4* xr = (const float4*)(x + row * NDIM);
    float4 v0 = xr[lane * 2], v1 = xr[lane * 2 + 1];
    float s = v0.x*v0.x + v0.y*v0.y + v0.z*v0.z + v0.w*v0.w
            + v1.x*v1.x + v1.y*v1.y + v1.z*v1.z + v1.w*v1.w;
#pragma unroll
    for (int off = 32; off; off >>= 1) s += __shfl_xor(s, off, 64);
    float scale = 22.627416997969522f / fmaxf(sqrtf(s), 1e-12f);
    const float4* gr = (const float4*)gamma;
    float4 g0 = gr[lane * 2], g1 = gr[lane * 2 + 1];
    u16x8 o;
    o[0] = f2bf(v0.x * scale * g0.x);
    o[1] = f2bf(v0.y * scale * g0.y);
    o[2] = f2bf(v0.z * scale * g0.z);
    o[3] = f2bf(v0.w * scale * g0.w);
    o[4] = f2bf(v1.x * scale * g1.x);
    o[5] = f2bf(v1.y * scale * g1.y);
    o[6] = f2bf(v1.z * scale * g1.z);
    o[7] = f2bf(v1.w * scale * g1.w);
    *(u16x8*)(xn + row * NDIM + lane * 8) = o;
  } else if (bid < 8960) {
    // transpose+cast 32x32 tiles
    int id = bid - 8192;
    const float* src;
    ushort_t* dst;
    int srcStride, ni, ki;
    if (id < 512) { ni = id & 31; ki = id >> 5; src = w_qkv; dst = wqkT; srcStride = QKVN; }
    else { id -= 512; ni = id & 15; ki = id >> 4; src = w_out; dst = woutT; srcStride = NDIM; }
    int tr = t >> 3;
    int tc = (t & 7) * 4;
    float4 v = *(const float4*)(src + (size_t)(ki * 32 + tr) * srcStride + ni * 32 + tc);
    tile[tr][tc] = v.x; tile[tr][tc + 1] = v.y; tile[tr][tc + 2] = v.z; tile[tr][tc + 3] = v.w;
    __syncthreads();
    u16x4 o;
    o[0] = f2bf(tile[tc + 0][tr]);
    o[1] = f2bf(tile[tc + 1][tr]);
    o[2] = f2bf(tile[tc + 2][tr]);
    o[3] = f2bf(tile[tc + 3][tr]);
    *(u16x4*)(dst + (size_t)(ni * 32 + tr) * NDIM + ki * 32 + tc) = o;
  } else if (bid < 9088) {
    // wv cast: wv[c][j] = bf16(w_qkv[c][1024 + j])
    int id = bid - 8960;
    int f = id * 2048 + t * 8;
    int c = f >> 9, j = f & 511;
    float4 u0 = *(const float4*)(w_qkv + (size_t)c * QKVN + 1024 + j);
    float4 u1 = *(const float4*)(w_qkv + (size_t)c * QKVN + 1024 + j + 4);
    u16x8 o;
    o[0] = f2bf(u0.x); o[1] = f2bf(u0.y); o[2] = f2bf(u0.z); o[3] = f2bf(u0.w);
    o[4] = f2bf(u1.x); o[5] = f2bf(u1.y); o[6] = f2bf(u1.z); o[7] = f2bf(u1.w);
    *(u16x8*)(wv + (size_t)c * 512 + j) = o;
  } else {
    // zero S (8 MB f32)
    int id = bid - 9088;   // 0..511, 4096 f32 per block
    f32x4 z = {};
#pragma unroll
    for (int i = 0; i < 4; ++i)
      *(f32x4*)(S + (size_t)id * 4096 + i * 1024 + t * 4) = z;
  }
}

// ---------------------------------------------------------------------------
// K2: xnT[c][n] = xn[n][c]  (bf16, 64x64 LDS tiles)
// ---------------------------------------------------------------------------
__global__ __launch_bounds__(256) void xnt_k(const ushort_t* __restrict__ xn,
                                             ushort_t* __restrict__ xnT) {
  __shared__ ushort_t tile[64 * 72];
  int nt = blockIdx.x & 511, ct = blockIdx.x >> 9;
  int n0 = nt * 64, c0 = ct * 64;
  int t = threadIdx.x;
  int row = t >> 2, cc = (t & 3) * 16;
  *(u16x8*)(tile + row * 72 + cc)     = *(const u16x8*)(xn + (size_t)(n0 + row) * NDIM + c0 + cc);
  *(u16x8*)(tile + row * 72 + cc + 8) = *(const u16x8*)(xn + (size_t)(n0 + row) * NDIM + c0 + cc + 8);
  __syncthreads();
  int oc = t >> 2, on = (t & 3) * 16;
  u16x8 a, b;
#pragma unroll
  for (int i = 0; i < 8; ++i) {
    a[i] = tile[(on + i) * 72 + oc];
    b[i] = tile[(on + 8 + i) * 72 + oc];
  }
  *(u16x8*)(xnT + (size_t)(c0 + oc) * ROWS + n0 + on)     = a;
  *(u16x8*)(xnT + (size_t)(c0 + oc) * ROWS + n0 + on + 8) = b;
}

// ---------------------------------------------------------------------------
// 256x128 counted-vmcnt ring core (verified R1 structure), generalized:
// NT k-tiles of 64; OMODE 1 = f32 bounce store, 2 = f32 atomicAdd.
// ---------------------------------------------------------------------------
template <int NT, int OMODE>
__device__ __forceinline__ void ring_core(
    const ushort_t* __restrict__ A, size_t strideA, size_t m0,
    const ushort_t* __restrict__ B, size_t strideB,
    float* __restrict__ C, size_t strideC, size_t crow0, size_t n0,
    ushort_t* sm) {
  const int tid  = threadIdx.x;
  const int lane = tid & 63;
  const int wave = tid >> 6;
  const int srow = lane >> 3;
  const int scol = ((lane & 7) ^ srow) * 16;
  const int r = lane & 15, q = lane >> 4;
  const int wm = (wave >> 1) * 64;
  const int wn = (wave & 1) * 64;

  ushort_t* As = sm;              // 3 x 16384 ushorts
  ushort_t* Bs = sm + 49152;      // 3 x 8192 ushorts

  auto stageA = [&](int t2, int g) {
    gload_lds16((const char*)(A + (m0 + (size_t)(g * 8 + srow)) * strideA + t2 * 64) + scol,
                (char*)(As + (t2 % 3) * 16384 + g * 512));
  };
  auto stageB = [&](int t2, int g) {
    gload_lds16((const char*)(B + (size_t)(g * 8 + srow) * strideB + t2 * 64) + scol,
                (char*)(Bs + (t2 % 3) * 8192 + g * 512));
  };

#pragma unroll
  for (int t2 = 0; t2 < 2; ++t2) {
#pragma unroll
    for (int a = 0; a < 4; ++a) stageA(t2, wave * 4 + a);
#pragma unroll
    for (int bb = 0; bb < 2; ++bb) stageB(t2, wave * 2 + bb);
  }
  asm volatile("s_waitcnt vmcnt(6)" ::: "memory");
  __builtin_amdgcn_s_barrier();

  f32x4 acc[4][4] = {};

#pragma unroll
  for (int t = 0; t < NT; ++t) {
    const ushort_t* Ab = As + (t % 3) * 16384;
    const ushort_t* Bb = Bs + (t % 3) * 8192;
#pragma unroll
    for (int ph = 0; ph < 2; ++ph) {
      const int kb = ph * 4 + q;
      bf16x8 af[4], bfr[4];
#pragma unroll
      for (int i = 0; i < 4; ++i) {
        int row = wm + i * 16 + r;
        af[i] = *(const bf16x8*)(const void*)(Ab + row * 64 + ((kb ^ (row & 7)) << 3));
      }
#pragma unroll
      for (int j = 0; j < 4; ++j) {
        int row = wn + j * 16 + r;
        bfr[j] = *(const bf16x8*)(const void*)(Bb + row * 64 + ((kb ^ (row & 7)) << 3));
      }
      if (t < NT - 2) {
        int t2 = t + 2;
        if (ph == 0) { stageA(t2, wave * 4 + 0); stageA(t2, wave * 4 + 1); stageB(t2, wave * 2 + 0); }
        else         { stageA(t2, wave * 4 + 2); stageA(t2, wave * 4 + 3); stageB(t2, wave * 2 + 1); }
      }
      __builtin_amdgcn_s_barrier();
      asm volatile("s_waitcnt lgkmcnt(0)" ::: "memory");
      __builtin_amdgcn_s_setprio(1);
#pragma unroll
      for (int i = 0; i < 4; ++i)
#pragma unroll
        for (int j = 0; j < 4; ++j)
          acc[i][j] = __builtin_amdgcn_mfma_f32_16x16x32_bf16(af[i], bfr[j], acc[i][j], 0, 0, 0);
      __builtin_amdgcn_s_setprio(0);
      if (ph == 1) {
        if (t < NT - 2)       { asm volatile("s_waitcnt vmcnt(6)" ::: "memory"); }
        else if (t == NT - 2) { asm volatile("s_waitcnt vmcnt(0)" ::: "memory"); }
      }
      __builtin_amdgcn_s_barrier();
    }
  }

  if constexpr (OMODE == 2) {
    // direct f32 atomic accumulate (K-split partials)
#pragma unroll
    for (int i = 0; i < 4; ++i)
#pragma unroll
      for (int j = 0; j < 4; ++j)
#pragma unroll
        for (int v = 0; v < 4; ++v)
          atomicAdd(&C[(crow0 + wm + i * 16 + q * 4 + v) * strideC + n0 + wn + j * 16 + r],
                    acc[i][j][v]);
  } else {
    // two-phase f32 LDS-bounce, coalesced stores
    float* Cf = (float*)sm;                 // [128][132] f32
#pragma unroll
    for (int p = 0; p < 2; ++p) {
      __syncthreads();
      if (((wave >> 2) & 1) == p) {
#pragma unroll
        for (int i = 0; i < 4; ++i)
#pragma unroll
          for (int j = 0; j < 4; ++j)
#pragma unroll
            for (int v = 0; v < 4; ++v)
              Cf[((wm & 127) + i * 16 + q * 4 + v) * 132 + wn + j * 16 + r] = acc[i][j][v];
      }
      __syncthreads();
      int row = tid >> 2;
      int c0 = (tid & 3) * 4;
#pragma unroll
      for (int it = 0; it < 8; ++it) {
        int col = c0 + it * 16;
        f32x4 val = *(const f32x4*)(Cf + row * 132 + col);
        *(f32x4*)(C + (crow0 + p * 128 + row) * strideC + n0 + col) = val;
      }
    }
  }
}

// ---------------------------------------------------------------------------
// K3: S_b += XnT_b * XnT_b^T-contraction-over-n, K-split 4 (atomic f32).
// Grid 256 = b(8) x [ks(4) x mt(2) x nt(4)], 512 threads.
// ---------------------------------------------------------------------------
__global__ __launch_bounds__(512, 2) void syrk_k(const ushort_t* __restrict__ xnT,
                                                 float* __restrict__ S) {
  __shared__ __align__(16) ushort_t sm[73728];   // 144 KB
  const int flat = blockIdx.x;
  const int b = flat & 7;
  const int local = flat >> 3;        // 0..31
  const int ks = local & 3;
  const int tl = local >> 2;          // 0..7
  const int mt = tl >> 2, nt = tl & 3;
  const size_t m0 = (size_t)mt * 256;
  const size_t n0 = (size_t)nt * 128;
  const ushort_t* Abase = xnT + (size_t)b * NSEQ + (size_t)ks * 1024;
  ring_core<16, 2>(Abase, ROWS, m0,
                   Abase + n0 * ROWS, ROWS,
                   S + (size_t)b * 262144, 512, m0, n0, sm);
}

// ---------------------------------------------------------------------------
// K4: PT[b][kd][c] = sum_c' wqkT[kd][c'] * S_b[c][c']   (S symmetric)
// Tiles 128x128, 256 threads, simple double-barrier loop. B staged f32->bf16.
// ---------------------------------------------------------------------------
__global__ __launch_bounds__(256) void pt_k(const ushort_t* __restrict__ wqkT,
                                            const float* __restrict__ S,
                                            ushort_t* __restrict__ PT) {
  __shared__ __align__(16) ushort_t As[8192];   // [128][64] swizzled
  __shared__ __align__(16) ushort_t Bs[8192];
  const int flat = blockIdx.x;        // 256 = b(8) x mt(8) x nt(4)
  const int b = flat & 7;
  const int local = flat >> 3;
  const int mt = local >> 2, nt = local & 3;
  const int m0 = mt * 128, n0 = nt * 128;
  const int tid = threadIdx.x;
  const int lane = tid & 63, wave = tid >> 6;
  const int srow = lane >> 3;
  const int scol = ((lane & 7) ^ srow) * 16;
  const int r = lane & 15, q = lane >> 4;
  const int wm = (wave >> 1) * 64, wn = (wave & 1) * 64;
  const float* Sb = S + (size_t)b * 262144;
  const int brow = tid >> 1, bhalf = tid & 1;

  f32x4 acc[4][4] = {};
  for (int k0 = 0; k0 < 512; k0 += 64) {
    __syncthreads();
#pragma unroll
    for (int c = 0; c < 4; ++c) {
      int g = wave * 4 + c;
      gload_lds16((const char*)(wqkT + (size_t)(m0 + g * 8 + srow) * 512 + k0) + scol,
                  (char*)(As + g * 512));
    }
    {
      const float* src = Sb + (size_t)(n0 + brow) * 512 + k0 + bhalf * 32;
#pragma unroll
      for (int u = 0; u < 4; ++u) {
        float4 f0 = *(const float4*)(src + u * 8);
        float4 f1 = *(const float4*)(src + u * 8 + 4);
        u16x8 o;
        o[0] = f2bf(f0.x); o[1] = f2bf(f0.y); o[2] = f2bf(f0.z); o[3] = f2bf(f0.w);
        o[4] = f2bf(f1.x); o[5] = f2bf(f1.y); o[6] = f2bf(f1.z); o[7] = f2bf(f1.w);
        int c8 = bhalf * 4 + u;
        *(u16x8*)(Bs + brow * 64 + ((c8 ^ (brow & 7)) << 3)) = o;
      }
    }
    __syncthreads();
#pragma unroll
    for (int ph = 0; ph < 2; ++ph) {
      const int kb = ph * 4 + q;
      bf16x8 af[4], bfr[4];
#pragma unroll
      for (int i = 0; i < 4; ++i) {
        int row = wm + i * 16 + r;
        af[i] = *(const bf16x8*)(const void*)(As + row * 64 + ((kb ^ (row & 7)) << 3));
      }
#pragma unroll
      for (int j = 0; j < 4; ++j) {
        int row = wn + j * 16 + r;
        bfr[j] = *(const bf16x8*)(const void*)(Bs + row * 64 + ((kb ^ (row & 7)) << 3));
      }
#pragma unroll
      for (int i = 0; i < 4; ++i)
#pragma unroll
        for (int j = 0; j < 4; ++j)
          acc[i][j] = __builtin_amdgcn_mfma_f32_16x16x32_bf16(af[i], bfr[j], acc[i][j], 0, 0, 0);
    }
  }
  ushort_t* dst = PT + (size_t)b * 524288;
#pragma unroll
  for (int i = 0; i < 4; ++i)
#pragma unroll
    for (int j = 0; j < 4; ++j)
#pragma unroll
      for (int v = 0; v < 4; ++v)
        dst[(size_t)(m0 + wm + i * 16 + q * 4 + v) * 512 + n0 + wn + j * 16 + r] =
            f2bf(acc[i][j][v]);
}

// ---------------------------------------------------------------------------
// K5a: per (b,h): G = Wq^T S Wk via wqkT/PT rows, norms via rowdots,
// softmax over e, write attnT[bh][e][d] bf16.
// ---------------------------------------------------------------------------
__global__ __launch_bounds__(256) void gsm_k(const ushort_t* __restrict__ wqkT,
                                             const ushort_t* __restrict__ PT,
                                             const float* __restrict__ temp,
                                             ushort_t* __restrict__ attnT) {
  int bh = blockIdx.x;
  int b = bh >> 3, h = bh & 7;
  int hb = h * 64;
  __shared__ float Gf[64][68];
  __shared__ float kq[128];
  int t = threadIdx.x, lane = t & 63, wave = t >> 6;
  int r = lane & 15, q = lane >> 4;
  const ushort_t* ptb = PT + (size_t)b * 524288;

  f32x4 acc[4] = {};
  const ushort_t* arow = wqkT + (size_t)(hb + wave * 16 + r) * 512;
#pragma unroll
  for (int kk = 0; kk < 512; kk += 32) {
    bf16x8 a = *(const bf16x8*)(arow + kk + q * 8);
#pragma unroll
    for (int j = 0; j < 4; ++j) {
      bf16x8 bb = *(const bf16x8*)(ptb + (size_t)(512 + hb + j * 16 + r) * 512 + kk + q * 8);
      acc[j] = __builtin_amdgcn_mfma_f32_16x16x32_bf16(a, bb, acc[j], 0, 0, 0);
    }
  }
#pragma unroll
  for (int j = 0; j < 4; ++j)
#pragma unroll
    for (int v = 0; v < 4; ++v)
      Gf[wave * 16 + q * 4 + v][j * 16 + r] = acc[j][v];
  if (t < 128) {
    int row = (t < 64) ? (hb + t) : (512 + hb + (t - 64));
    const ushort_t* wr = wqkT + (size_t)row * 512;
    const ushort_t* pr = ptb + (size_t)row * 512;
    float s = 0.f;
    for (int i = 0; i < 512; i += 8) {
      u16x8 wa = *(const u16x8*)(wr + i);
      u16x8 pa = *(const u16x8*)(pr + i);
#pragma unroll
      for (int e2 = 0; e2 < 8; ++e2) s += bf2f(wa[e2]) * bf2f(pa[e2]);
    }
    kq[t] = s;
  }
  __syncthreads();

  int d = t >> 2, eg = (t & 3) * 16;
  float qn = fmaxf(sqrtf(kq[d]), 1e-12f);
  float scale = 8.0f * expf(temp[h]) / qn;
  float row[16];
#pragma unroll
  for (int k = 0; k < 16; ++k)
    row[k] = Gf[d][eg + k] * scale / fmaxf(sqrtf(kq[64 + eg + k]), 1e-12f);
  float mx = -1e30f;
#pragma unroll
  for (int k = 0; k < 16; ++k) mx = fmaxf(mx, row[k]);
  mx = fmaxf(mx, __shfl_xor(mx, 1, 64));
  mx = fmaxf(mx, __shfl_xor(mx, 2, 64));
  float s = 0.f;
#pragma unroll
  for (int k = 0; k < 16; ++k) { row[k] = expf(row[k] - mx); s += row[k]; }
  s += __shfl_xor(s, 1, 64);
  s += __shfl_xor(s, 2, 64);
  float inv = 1.0f / s;
#pragma unroll
  for (int k = 0; k < 16; ++k)
    attnT[(size_t)bh * 4096 + (eg + k) * 64 + d] = f2bf(row[k] * inv);
}

// ---------------------------------------------------------------------------
// K5b: MT[b][c'][c] = sum_h sum_e (sum_d woutT[c'][hd]*attnT[bh][e][d]) * wv[c][hE]
// Per h: stage AT_h [128 c' x 64 e] in LDS, then accumulate MT via MFMA.
// Grid 128 = b(8) x mq(4) x nq(4)... (mq,nq) 16 tiles of [128x128].
// ---------------------------------------------------------------------------
__global__ __launch_bounds__(256) void atmt_k(const ushort_t* __restrict__ woutT,
                                              const ushort_t* __restrict__ attnT,
                                              const ushort_t* __restrict__ wv,
                                              ushort_t* __restrict__ MT) {
  __shared__ ushort_t at[128 * 72];
  const int flat = blockIdx.x;     // 128
  const int b = flat & 7;
  const int local = flat >> 3;     // 0..15
  const int mq = local >> 2, nq = local & 3;
  int t = threadIdx.x, lane = t & 63, w = t >> 6;
  int r = lane & 15, q = lane >> 4;
  int wm2 = (w >> 1) * 64, wn2 = (w & 1) * 64;
  f32x4 acc2[4][4] = {};
  for (int h = 0; h < 8; ++h) {
    int hb = h * 64;
    const ushort_t* atn = attnT + (size_t)(b * 8 + h) * 4096;
    f32x4 acc1[2][4] = {};
#pragma unroll
    for (int kk = 0; kk < 64; kk += 32) {
      bf16x8 a[2], bb[4];
#pragma unroll
      for (int i = 0; i < 2; ++i)
        a[i] = *(const bf16x8*)(woutT + (size_t)(mq * 128 + w * 32 + i * 16 + r) * 512 + hb + kk + q * 8);
#pragma unroll
      for (int j = 0; j < 4; ++j)
        bb[j] = *(const bf16x8*)(atn + (j * 16 + r) * 64 + kk + q * 8);
#pragma unroll
      for (int i = 0; i < 2; ++i)
#pragma unroll
        for (int j = 0; j < 4; ++j)
          acc1[i][j] = __builtin_amdgcn_mfma_f32_16x16x32_bf16(a[i], bb[j], acc1[i][j], 0, 0, 0);
    }
    __syncthreads();
#pragma unroll
    for (int i = 0; i < 2; ++i)
#pragma unroll
      for (int j = 0; j < 4; ++j)
#pragma unroll
        for (int v = 0; v < 4; ++v)
          at[(w * 32 + i * 16 + q * 4 + v) * 72 + j * 16 + r] = f2bf(acc1[i][j][v]);
    __syncthreads();
#pragma unroll
    for (int kk = 0; kk < 64; kk += 32) {
      bf16x8 a2[4], b2[4];
#pragma unroll
      for (int i = 0; i < 4; ++i)
        a2[i] = *(const bf16x8*)(const void*)(at + (wm2 + i * 16 + r) * 72 + kk + q * 8);
#pragma unroll
      for (int j = 0; j < 4; ++j)
        b2[j] = *(const bf16x8*)(wv + (size_t)(nq * 128 + wn2 + j * 16 + r) * 512 + hb + kk + q * 8);
#pragma unroll
      for (int i = 0; i < 4; ++i)
#pragma unroll
        for (int j = 0; j < 4; ++j)
          acc2[i][j] = __builtin_amdgcn_mfma_f32_16x16x32_bf16(a2[i], b2[j], acc2[i][j], 0, 0, 0);
    }
  }
#pragma unroll
  for (int i = 0; i < 4; ++i)
#pragma unroll
    for (int j = 0; j < 4; ++j)
#pragma unroll
      for (int v = 0; v < 4; ++v)
        MT[(size_t)b * 262144 + (size_t)(mq * 128 + wm2 + i * 16 + q * 4 + v) * 512 +
           nq * 128 + wn2 + j * 16 + r] = f2bf(acc2[i][j][v]);
}

// ---------------------------------------------------------------------------
// K6: out_b = Xn_b @ MT_b^T  (ring core, f32 bounce out)
// ---------------------------------------------------------------------------
__global__ __launch_bounds__(512, 2) void final_k(const ushort_t* __restrict__ xn,
                                                  const ushort_t* __restrict__ MT,
                                                  float* __restrict__ out) {
  __shared__ __align__(16) ushort_t sm[73728];   // 144 KB
  const int flat = blockIdx.x;       // 512: xcd = b
  const int b = flat & 7;
  const int local = flat >> 3;       // 0..63
  const int mt = local >> 2, nt = local & 3;
  const size_t m0 = (size_t)b * NSEQ + (size_t)mt * 256;
  const size_t n0 = (size_t)nt * 128;
  ring_core<8, 1>(xn, NDIM, m0,
                  MT + (size_t)b * 262144 + n0 * 512, 512,
                  out, NDIM, m0, n0, sm);
}

extern "C" void kernel_launch(void* const* d_in, const int* in_sizes, int n_in,
                              void* d_out, int out_size, void* d_ws, size_t ws_size,
                              hipStream_t stream) {
  (void)in_sizes; (void)n_in; (void)out_size; (void)ws_size;
  const float* x     = (const float*)d_in[0];
  const float* gamma = (const float*)d_in[1];
  const float* w_qkv = (const float*)d_in[2];
  const float* temp  = (const float*)d_in[3];
  const float* w_out = (const float*)d_in[4];
  float* out = (float*)d_out;
  char* ws = (char*)d_ws;

  // workspace layout (~86.5 MB):
  ushort_t* xn    = (ushort_t*)ws;                              // 32 MB
  ushort_t* xnT   = (ushort_t*)(ws + (size_t)33554432);         // 32 MB
  float*    S     = (float*)   (ws + (size_t)67108864);         // 8 MB f32
  ushort_t* PT    = (ushort_t*)(ws + (size_t)75497472);         // 8 MB
  ushort_t* MT    = (ushort_t*)(ws + (size_t)83886080);         // 4 MB
  ushort_t* attnT = (ushort_t*)(ws + (size_t)88080384);         // 0.5 MB
  ushort_t* wqkT  = (ushort_t*)(ws + (size_t)88604672);         // 1 MB
  ushort_t* woutT = (ushort_t*)(ws + (size_t)89653248);         // 0.5 MB
  ushort_t* wv    = (ushort_t*)(ws + (size_t)90177536);         // 0.5 MB

  prep_rms_k<<<9600, 256, 0, stream>>>(x, gamma, xn, w_qkv, w_out, wqkT, woutT, wv, S);
  xnt_k<<<4096, 256, 0, stream>>>(xn, xnT);
  syrk_k<<<256, 512, 0, stream>>>(xnT, S);
  pt_k<<<256, 256, 0, stream>>>(wqkT, S, PT);
  gsm_k<<<64, 256, 0, stream>>>(wqkT, PT, temp, attnT);
  atmt_k<<<128, 256, 0, stream>>>(woutT, attnT, wv, MT);
  final_k<<<512, 512, 0, stream>>>(xn, MT, out);
}

// Round 6
// 269.421 us; speedup vs baseline: 1.0078x; 1.0078x over previous
//
#include <hip/hip_runtime.h>
#include <stdint.h>

#define NDIM 512
#define HEADS 8
#define DHEAD 64
#define NSEQ 4096
#define BATCH 8
#define ROWS (BATCH * NSEQ)   // 32768
#define QKVN (3 * NDIM)       // 1536
#define XSTR 32832            // padded xnT row stride (+64 elems = 128 B)

typedef unsigned short ushort_t;
typedef __bf16 bf16x8 __attribute__((ext_vector_type(8)));
typedef float f32x4 __attribute__((ext_vector_type(4)));
typedef unsigned short u16x8 __attribute__((ext_vector_type(8)));
typedef unsigned short u16x4 __attribute__((ext_vector_type(4)));

__device__ __forceinline__ ushort_t f2bf(float f) {
  union { float f; uint32_t u; } v; v.f = f;
  uint32_t r = (v.u + 0x7FFFu + ((v.u >> 16) & 1u)) >> 16;
  return (ushort_t)r;
}
__device__ __forceinline__ float bf2f(ushort_t h) {
  union { uint32_t u; float f; } v; v.u = ((uint32_t)h) << 16;
  return v.f;
}

__device__ __forceinline__ void gload_lds16(const void* g, void* l) {
  __builtin_amdgcn_global_load_lds(
      (__attribute__((address_space(1))) void*)(g),
      (__attribute__((address_space(3))) void*)(l), 16, 0, 0);
}

// ---------------------------------------------------------------------------
// K1: fused prep. Grid layout (256 threads each):
//   [0,8192)       rmsnorm (4 rows/block) -> xn bf16
//   [8192,8704)    wqkT transpose: w_qkv cols 0..1023 -> wqkT[1024][512]
//   [8704,8960)    woutT transpose: w_out -> woutT[512][512]
//   [8960,9088)    wv cast: w_qkv cols 1024..1535 -> wv[512 c][512 hE] bf16
//   [9088,9600)    zero S f32 (8 MB)
// ---------------------------------------------------------------------------
__global__ __launch_bounds__(256) void prep_rms_k(const float* __restrict__ x,
                                                  const float* __restrict__ gamma,
                                                  ushort_t* __restrict__ xn,
                                                  const float* __restrict__ w_qkv,
                                                  const float* __restrict__ w_out,
                                                  ushort_t* __restrict__ wqkT,
                                                  ushort_t* __restrict__ woutT,
                                                  ushort_t* __restrict__ wv,
                                                  float* __restrict__ S) {
  __shared__ float tile[32][33];
  int bid = blockIdx.x;
  int t = threadIdx.x;
  if (bid < 8192) {
    int wave = t >> 6, lane = t & 63;
    size_t row = (size_t)bid * 4 + wave;
    const float4* xr = (const float4*)(x + row * NDIM);
    float4 v0 = xr[lane * 2], v1 = xr[lane * 2 + 1];
    float s = v0.x*v0.x + v0.y*v0.y + v0.z*v0.z + v0.w*v0.w
            + v1.x*v1.x + v1.y*v1.y + v1.z*v1.z + v1.w*v1.w;
#pragma unroll
    for (int off = 32; off; off >>= 1) s += __shfl_xor(s, off, 64);
    float scale = 22.627416997969522f / fmaxf(sqrtf(s), 1e-12f);
    const float4* gr = (const float4*)gamma;
    float4 g0 = gr[lane * 2], g1 = gr[lane * 2 + 1];
    u16x8 o;
    o[0] = f2bf(v0.x * scale * g0.x);
    o[1] = f2bf(v0.y * scale * g0.y);
    o[2] = f2bf(v0.z * scale * g0.z);
    o[3] = f2bf(v0.w * scale * g0.w);
    o[4] = f2bf(v1.x * scale * g1.x);
    o[5] = f2bf(v1.y * scale * g1.y);
    o[6] = f2bf(v1.z * scale * g1.z);
    o[7] = f2bf(v1.w * scale * g1.w);
    *(u16x8*)(xn + row * NDIM + lane * 8) = o;
  } else if (bid < 8960) {
    // transpose+cast 32x32 tiles
    int id = bid - 8192;
    const float* src;
    ushort_t* dst;
    int srcStride, ni, ki;
    if (id < 512) { ni = id & 31; ki = id >> 5; src = w_qkv; dst = wqkT; srcStride = QKVN; }
    else { id -= 512; ni = id & 15; ki = id >> 4; src = w_out; dst = woutT; srcStride = NDIM; }
    int tr = t >> 3;
    int tc = (t & 7) * 4;
    float4 v = *(const float4*)(src + (size_t)(ki * 32 + tr) * srcStride + ni * 32 + tc);
    tile[tr][tc] = v.x; tile[tr][tc + 1] = v.y; tile[tr][tc + 2] = v.z; tile[tr][tc + 3] = v.w;
    __syncthreads();
    u16x4 o;
    o[0] = f2bf(tile[tc + 0][tr]);
    o[1] = f2bf(tile[tc + 1][tr]);
    o[2] = f2bf(tile[tc + 2][tr]);
    o[3] = f2bf(tile[tc + 3][tr]);
    *(u16x4*)(dst + (size_t)(ni * 32 + tr) * NDIM + ki * 32 + tc) = o;
  } else if (bid < 9088) {
    // wv cast: wv[c][j] = bf16(w_qkv[c][1024 + j])
    int id = bid - 8960;
    int f = id * 2048 + t * 8;
    int c = f >> 9, j = f & 511;
    float4 u0 = *(const float4*)(w_qkv + (size_t)c * QKVN + 1024 + j);
    float4 u1 = *(const float4*)(w_qkv + (size_t)c * QKVN + 1024 + j + 4);
    u16x8 o;
    o[0] = f2bf(u0.x); o[1] = f2bf(u0.y); o[2] = f2bf(u0.z); o[3] = f2bf(u0.w);
    o[4] = f2bf(u1.x); o[5] = f2bf(u1.y); o[6] = f2bf(u1.z); o[7] = f2bf(u1.w);
    *(u16x8*)(wv + (size_t)c * 512 + j) = o;
  } else {
    // zero S (8 MB f32)
    int id = bid - 9088;   // 0..511, 4096 f32 per block
    f32x4 z = {};
#pragma unroll
    for (int i = 0; i < 4; ++i)
      *(f32x4*)(S + (size_t)id * 4096 + i * 1024 + t * 4) = z;
  }
}

// ---------------------------------------------------------------------------
// K2: xnT[c][n] = xn[n][c]  (bf16, 64x64 LDS tiles), PADDED row stride XSTR
// ---------------------------------------------------------------------------
__global__ __launch_bounds__(256) void xnt_k(const ushort_t* __restrict__ xn,
                                             ushort_t* __restrict__ xnT) {
  __shared__ ushort_t tile[64 * 72];
  int nt = blockIdx.x & 511, ct = blockIdx.x >> 9;
  int n0 = nt * 64, c0 = ct * 64;
  int t = threadIdx.x;
  int row = t >> 2, cc = (t & 3) * 16;
  *(u16x8*)(tile + row * 72 + cc)     = *(const u16x8*)(xn + (size_t)(n0 + row) * NDIM + c0 + cc);
  *(u16x8*)(tile + row * 72 + cc + 8) = *(const u16x8*)(xn + (size_t)(n0 + row) * NDIM + c0 + cc + 8);
  __syncthreads();
  int oc = t >> 2, on = (t & 3) * 16;
  u16x8 a, b;
#pragma unroll
  for (int i = 0; i < 8; ++i) {
    a[i] = tile[(on + i) * 72 + oc];
    b[i] = tile[(on + 8 + i) * 72 + oc];
  }
  *(u16x8*)(xnT + (size_t)(c0 + oc) * XSTR + n0 + on)     = a;
  *(u16x8*)(xnT + (size_t)(c0 + oc) * XSTR + n0 + on + 8) = b;
}

// ---------------------------------------------------------------------------
// 256x128 counted-vmcnt ring core (verified R1 structure), generalized:
// NT k-tiles of 64; OMODE 1 = f32 bounce store, 2 = f32 atomicAdd.
// Rule-#18 hardening: sched_barrier(0) after the lgkmcnt(0) wait so MFMA
// cannot be hoisted above the LDS-read drain.
// ---------------------------------------------------------------------------
template <int NT, int OMODE>
__device__ __forceinline__ void ring_core(
    const ushort_t* __restrict__ A, size_t strideA, size_t m0,
    const ushort_t* __restrict__ B, size_t strideB,
    float* __restrict__ C, size_t strideC, size_t crow0, size_t n0,
    ushort_t* sm) {
  const int tid  = threadIdx.x;
  const int lane = tid & 63;
  const int wave = tid >> 6;
  const int srow = lane >> 3;
  const int scol = ((lane & 7) ^ srow) * 16;
  const int r = lane & 15, q = lane >> 4;
  const int wm = (wave >> 1) * 64;
  const int wn = (wave & 1) * 64;

  ushort_t* As = sm;              // 3 x 16384 ushorts
  ushort_t* Bs = sm + 49152;      // 3 x 8192 ushorts

  auto stageA = [&](int t2, int g) {
    gload_lds16((const char*)(A + (m0 + (size_t)(g * 8 + srow)) * strideA + t2 * 64) + scol,
                (char*)(As + (t2 % 3) * 16384 + g * 512));
  };
  auto stageB = [&](int t2, int g) {
    gload_lds16((const char*)(B + (size_t)(g * 8 + srow) * strideB + t2 * 64) + scol,
                (char*)(Bs + (t2 % 3) * 8192 + g * 512));
  };

#pragma unroll
  for (int t2 = 0; t2 < 2; ++t2) {
#pragma unroll
    for (int a = 0; a < 4; ++a) stageA(t2, wave * 4 + a);
#pragma unroll
    for (int bb = 0; bb < 2; ++bb) stageB(t2, wave * 2 + bb);
  }
  asm volatile("s_waitcnt vmcnt(6)" ::: "memory");
  __builtin_amdgcn_s_barrier();

  f32x4 acc[4][4] = {};

#pragma unroll
  for (int t = 0; t < NT; ++t) {
    const ushort_t* Ab = As + (t % 3) * 16384;
    const ushort_t* Bb = Bs + (t % 3) * 8192;
#pragma unroll
    for (int ph = 0; ph < 2; ++ph) {
      const int kb = ph * 4 + q;
      bf16x8 af[4], bfr[4];
#pragma unroll
      for (int i = 0; i < 4; ++i) {
        int row = wm + i * 16 + r;
        af[i] = *(const bf16x8*)(const void*)(Ab + row * 64 + ((kb ^ (row & 7)) << 3));
      }
#pragma unroll
      for (int j = 0; j < 4; ++j) {
        int row = wn + j * 16 + r;
        bfr[j] = *(const bf16x8*)(const void*)(Bb + row * 64 + ((kb ^ (row & 7)) << 3));
      }
      if (t < NT - 2) {
        int t2 = t + 2;
        if (ph == 0) { stageA(t2, wave * 4 + 0); stageA(t2, wave * 4 + 1); stageB(t2, wave * 2 + 0); }
        else         { stageA(t2, wave * 4 + 2); stageA(t2, wave * 4 + 3); stageB(t2, wave * 2 + 1); }
      }
      __builtin_amdgcn_s_barrier();
      asm volatile("s_waitcnt lgkmcnt(0)" ::: "memory");
      __builtin_amdgcn_sched_barrier(0);
      __builtin_amdgcn_s_setprio(1);
#pragma unroll
      for (int i = 0; i < 4; ++i)
#pragma unroll
        for (int j = 0; j < 4; ++j)
          acc[i][j] = __builtin_amdgcn_mfma_f32_16x16x32_bf16(af[i], bfr[j], acc[i][j], 0, 0, 0);
      __builtin_amdgcn_s_setprio(0);
      if (ph == 1) {
        if (t < NT - 2)       { asm volatile("s_waitcnt vmcnt(6)" ::: "memory"); }
        else if (t == NT - 2) { asm volatile("s_waitcnt vmcnt(0)" ::: "memory"); }
      }
      __builtin_amdgcn_s_barrier();
    }
  }

  if constexpr (OMODE == 2) {
    // direct f32 atomic accumulate (K-split partials)
#pragma unroll
    for (int i = 0; i < 4; ++i)
#pragma unroll
      for (int j = 0; j < 4; ++j)
#pragma unroll
        for (int v = 0; v < 4; ++v)
          atomicAdd(&C[(crow0 + wm + i * 16 + q * 4 + v) * strideC + n0 + wn + j * 16 + r],
                    acc[i][j][v]);
  } else {
    // two-phase f32 LDS-bounce, coalesced stores
    float* Cf = (float*)sm;                 // [128][132] f32
#pragma unroll
    for (int p = 0; p < 2; ++p) {
      __syncthreads();
      if (((wave >> 2) & 1) == p) {
#pragma unroll
        for (int i = 0; i < 4; ++i)
#pragma unroll
          for (int j = 0; j < 4; ++j)
#pragma unroll
            for (int v = 0; v < 4; ++v)
              Cf[((wm & 127) + i * 16 + q * 4 + v) * 132 + wn + j * 16 + r] = acc[i][j][v];
      }
      __syncthreads();
      int row = tid >> 2;
      int c0 = (tid & 3) * 4;
#pragma unroll
      for (int it = 0; it < 8; ++it) {
        int col = c0 + it * 16;
        f32x4 val = *(const f32x4*)(Cf + row * 132 + col);
        *(f32x4*)(C + (crow0 + p * 128 + row) * strideC + n0 + col) = val;
      }
    }
  }
}

// ---------------------------------------------------------------------------
// K3: S_b += contraction over n of XnT_b, K-split 4 (atomic f32).
// Grid 256 = b(8) x [ks(4) x mt(2) x nt(4)], 512 threads.
// ---------------------------------------------------------------------------
__global__ __launch_bounds__(512, 2) void syrk_k(const ushort_t* __restrict__ xnT,
                                                 float* __restrict__ S) {
  __shared__ __align__(16) ushort_t sm[73728];   // 144 KB
  const int flat = blockIdx.x;
  const int b = flat & 7;
  const int local = flat >> 3;        // 0..31
  const int ks = local & 3;
  const int tl = local >> 2;          // 0..7
  const int mt = tl >> 2, nt = tl & 3;
  const size_t m0 = (size_t)mt * 256;
  const size_t n0 = (size_t)nt * 128;
  const ushort_t* Abase = xnT + (size_t)b * NSEQ + (size_t)ks * 1024;
  ring_core<16, 2>(Abase, XSTR, m0,
                   Abase + n0 * XSTR, XSTR,
                   S + (size_t)b * 262144, 512, m0, n0, sm);
}

// ---------------------------------------------------------------------------
// K4: PT[b][kd][c] = sum_c' wqkT[kd][c'] * S_b[c][c']   (R4 known-good version)
// Tiles 128x128, 256 threads, simple double-barrier loop. B staged f32->bf16.
// ---------------------------------------------------------------------------
__global__ __launch_bounds__(256) void pt_k(const ushort_t* __restrict__ wqkT,
                                            const float* __restrict__ S,
                                            ushort_t* __restrict__ PT) {
  __shared__ __align__(16) ushort_t As[8192];   // [128][64] swizzled
  __shared__ __align__(16) ushort_t Bs[8192];
  const int flat = blockIdx.x;        // 256 = b(8) x mt(8) x nt(4)
  const int b = flat & 7;
  const int local = flat >> 3;
  const int mt = local >> 2, nt = local & 3;
  const int m0 = mt * 128, n0 = nt * 128;
  const int tid = threadIdx.x;
  const int lane = tid & 63, wave = tid >> 6;
  const int srow = lane >> 3;
  const int scol = ((lane & 7) ^ srow) * 16;
  const int r = lane & 15, q = lane >> 4;
  const int wm = (wave >> 1) * 64, wn = (wave & 1) * 64;
  const float* Sb = S + (size_t)b * 262144;
  const int brow = tid >> 1, bhalf = tid & 1;

  f32x4 acc[4][4] = {};
  for (int k0 = 0; k0 < 512; k0 += 64) {
    __syncthreads();
#pragma unroll
    for (int c = 0; c < 4; ++c) {
      int g = wave * 4 + c;
      gload_lds16((const char*)(wqkT + (size_t)(m0 + g * 8 + srow) * 512 + k0) + scol,
                  (char*)(As + g * 512));
    }
    {
      const float* src = Sb + (size_t)(n0 + brow) * 512 + k0 + bhalf * 32;
#pragma unroll
      for (int u = 0; u < 4; ++u) {
        float4 f0 = *(const float4*)(src + u * 8);
        float4 f1 = *(const float4*)(src + u * 8 + 4);
        u16x8 o;
        o[0] = f2bf(f0.x); o[1] = f2bf(f0.y); o[2] = f2bf(f0.z); o[3] = f2bf(f0.w);
        o[4] = f2bf(f1.x); o[5] = f2bf(f1.y); o[6] = f2bf(f1.z); o[7] = f2bf(f1.w);
        int c8 = bhalf * 4 + u;
        *(u16x8*)(Bs + brow * 64 + ((c8 ^ (brow & 7)) << 3)) = o;
      }
    }
    __syncthreads();
#pragma unroll
    for (int ph = 0; ph < 2; ++ph) {
      const int kb = ph * 4 + q;
      bf16x8 af[4], bfr[4];
#pragma unroll
      for (int i = 0; i < 4; ++i) {
        int row = wm + i * 16 + r;
        af[i] = *(const bf16x8*)(const void*)(As + row * 64 + ((kb ^ (row & 7)) << 3));
      }
#pragma unroll
      for (int j = 0; j < 4; ++j) {
        int row = wn + j * 16 + r;
        bfr[j] = *(const bf16x8*)(const void*)(Bs + row * 64 + ((kb ^ (row & 7)) << 3));
      }
#pragma unroll
      for (int i = 0; i < 4; ++i)
#pragma unroll
        for (int j = 0; j < 4; ++j)
          acc[i][j] = __builtin_amdgcn_mfma_f32_16x16x32_bf16(af[i], bfr[j], acc[i][j], 0, 0, 0);
    }
  }
  ushort_t* dst = PT + (size_t)b * 524288;
#pragma unroll
  for (int i = 0; i < 4; ++i)
#pragma unroll
    for (int j = 0; j < 4; ++j)
#pragma unroll
      for (int v = 0; v < 4; ++v)
        dst[(size_t)(m0 + wm + i * 16 + q * 4 + v) * 512 + n0 + wn + j * 16 + r] =
            f2bf(acc[i][j][v]);
}

// ---------------------------------------------------------------------------
// K5a: per (b,h): G = Wq^T S Wk via wqkT/PT rows, norms via rowdots,
// softmax over e, write attnT[bh][e][d] bf16.
// ---------------------------------------------------------------------------
__global__ __launch_bounds__(256) void gsm_k(const ushort_t* __restrict__ wqkT,
                                             const ushort_t* __restrict__ PT,
                                             const float* __restrict__ temp,
                                             ushort_t* __restrict__ attnT) {
  int bh = blockIdx.x;
  int b = bh >> 3, h = bh & 7;
  int hb = h * 64;
  __shared__ float Gf[64][68];
  __shared__ float kq[128];
  int t = threadIdx.x, lane = t & 63, wave = t >> 6;
  int r = lane & 15, q = lane >> 4;
  const ushort_t* ptb = PT + (size_t)b * 524288;

  f32x4 acc[4] = {};
  const ushort_t* arow = wqkT + (size_t)(hb + wave * 16 + r) * 512;
#pragma unroll
  for (int kk = 0; kk < 512; kk += 32) {
    bf16x8 a = *(const bf16x8*)(arow + kk + q * 8);
#pragma unroll
    for (int j = 0; j < 4; ++j) {
      bf16x8 bb = *(const bf16x8*)(ptb + (size_t)(512 + hb + j * 16 + r) * 512 + kk + q * 8);
      acc[j] = __builtin_amdgcn_mfma_f32_16x16x32_bf16(a, bb, acc[j], 0, 0, 0);
    }
  }
#pragma unroll
  for (int j = 0; j < 4; ++j)
#pragma unroll
    for (int v = 0; v < 4; ++v)
      Gf[wave * 16 + q * 4 + v][j * 16 + r] = acc[j][v];
  if (t < 128) {
    int row = (t < 64) ? (hb + t) : (512 + hb + (t - 64));
    const ushort_t* wr = wqkT + (size_t)row * 512;
    const ushort_t* pr = ptb + (size_t)row * 512;
    float s = 0.f;
    for (int i = 0; i < 512; i += 8) {
      u16x8 wa = *(const u16x8*)(wr + i);
      u16x8 pa = *(const u16x8*)(pr + i);
#pragma unroll
      for (int e2 = 0; e2 < 8; ++e2) s += bf2f(wa[e2]) * bf2f(pa[e2]);
    }
    kq[t] = s;
  }
  __syncthreads();

  int d = t >> 2, eg = (t & 3) * 16;
  float qn = fmaxf(sqrtf(kq[d]), 1e-12f);
  float scale = 8.0f * expf(temp[h]) / qn;
  float row[16];
#pragma unroll
  for (int k = 0; k < 16; ++k)
    row[k] = Gf[d][eg + k] * scale / fmaxf(sqrtf(kq[64 + eg + k]), 1e-12f);
  float mx = -1e30f;
#pragma unroll
  for (int k = 0; k < 16; ++k) mx = fmaxf(mx, row[k]);
  mx = fmaxf(mx, __shfl_xor(mx, 1, 64));
  mx = fmaxf(mx, __shfl_xor(mx, 2, 64));
  float s = 0.f;
#pragma unroll
  for (int k = 0; k < 16; ++k) { row[k] = expf(row[k] - mx); s += row[k]; }
  s += __shfl_xor(s, 1, 64);
  s += __shfl_xor(s, 2, 64);
  float inv = 1.0f / s;
#pragma unroll
  for (int k = 0; k < 16; ++k)
    attnT[(size_t)bh * 4096 + (eg + k) * 64 + d] = f2bf(row[k] * inv);
}

// ---------------------------------------------------------------------------
// K5b: MT[b][c'][c] = sum_h sum_e (sum_d woutT[c'][hd]*attnT[bh][e][d]) * wv[c][hE]
// ---------------------------------------------------------------------------
__global__ __launch_bounds__(256) void atmt_k(const ushort_t* __restrict__ woutT,
                                              const ushort_t* __restrict__ attnT,
                                              const ushort_t* __restrict__ wv,
                                              ushort_t* __restrict__ MT) {
  __shared__ ushort_t at[128 * 72];
  const int flat = blockIdx.x;     // 128
  const int b = flat & 7;
  const int local = flat >> 3;     // 0..15
  const int mq = local >> 2, nq = local & 3;
  int t = threadIdx.x, lane = t & 63, w = t >> 6;
  int r = lane & 15, q = lane >> 4;
  int wm2 = (w >> 1) * 64, wn2 = (w & 1) * 64;
  f32x4 acc2[4][4] = {};
  for (int h = 0; h < 8; ++h) {
    int hb = h * 64;
    const ushort_t* atn = attnT + (size_t)(b * 8 + h) * 4096;
    f32x4 acc1[2][4] = {};
#pragma unroll
    for (int kk = 0; kk < 64; kk += 32) {
      bf16x8 a[2], bb[4];
#pragma unroll
      for (int i = 0; i < 2; ++i)
        a[i] = *(const bf16x8*)(woutT + (size_t)(mq * 128 + w * 32 + i * 16 + r) * 512 + hb + kk + q * 8);
#pragma unroll
      for (int j = 0; j < 4; ++j)
        bb[j] = *(const bf16x8*)(atn + (j * 16 + r) * 64 + kk + q * 8);
#pragma unroll
      for (int i = 0; i < 2; ++i)
#pragma unroll
        for (int j = 0; j < 4; ++j)
          acc1[i][j] = __builtin_amdgcn_mfma_f32_16x16x32_bf16(a[i], bb[j], acc1[i][j], 0, 0, 0);
    }
    __syncthreads();
#pragma unroll
    for (int i = 0; i < 2; ++i)
#pragma unroll
      for (int j = 0; j < 4; ++j)
#pragma unroll
        for (int v = 0; v < 4; ++v)
          at[(w * 32 + i * 16 + q * 4 + v) * 72 + j * 16 + r] = f2bf(acc1[i][j][v]);
    __syncthreads();
#pragma unroll
    for (int kk = 0; kk < 64; kk += 32) {
      bf16x8 a2[4], b2[4];
#pragma unroll
      for (int i = 0; i < 4; ++i)
        a2[i] = *(const bf16x8*)(const void*)(at + (wm2 + i * 16 + r) * 72 + kk + q * 8);
#pragma unroll
      for (int j = 0; j < 4; ++j)
        b2[j] = *(const bf16x8*)(wv + (size_t)(nq * 128 + wn2 + j * 16 + r) * 512 + hb + kk + q * 8);
#pragma unroll
      for (int i = 0; i < 4; ++i)
#pragma unroll
        for (int j = 0; j < 4; ++j)
          acc2[i][j] = __builtin_amdgcn_mfma_f32_16x16x32_bf16(a2[i], b2[j], acc2[i][j], 0, 0, 0);
    }
  }
#pragma unroll
  for (int i = 0; i < 4; ++i)
#pragma unroll
    for (int j = 0; j < 4; ++j)
#pragma unroll
      for (int v = 0; v < 4; ++v)
        MT[(size_t)b * 262144 + (size_t)(mq * 128 + wm2 + i * 16 + q * 4 + v) * 512 +
           nq * 128 + wn2 + j * 16 + r] = f2bf(acc2[i][j][v]);
}

// ---------------------------------------------------------------------------
// K6: out_b = Xn_b @ MT_b^T  (ring core, f32 bounce out)
// ---------------------------------------------------------------------------
__global__ __launch_bounds__(512, 2) void final_k(const ushort_t* __restrict__ xn,
                                                  const ushort_t* __restrict__ MT,
                                                  float* __restrict__ out) {
  __shared__ __align__(16) ushort_t sm[73728];   // 144 KB
  const int flat = blockIdx.x;       // 512: xcd = b
  const int b = flat & 7;
  const int local = flat >> 3;       // 0..63
  const int mt = local >> 2, nt = local & 3;
  const size_t m0 = (size_t)b * NSEQ + (size_t)mt * 256;
  const size_t n0 = (size_t)nt * 128;
  ring_core<8, 1>(xn, NDIM, m0,
                  MT + (size_t)b * 262144 + n0 * 512, 512,
                  out, NDIM, m0, n0, sm);
}

extern "C" void kernel_launch(void* const* d_in, const int* in_sizes, int n_in,
                              void* d_out, int out_size, void* d_ws, size_t ws_size,
                              hipStream_t stream) {
  (void)in_sizes; (void)n_in; (void)out_size; (void)ws_size;
  const float* x     = (const float*)d_in[0];
  const float* gamma = (const float*)d_in[1];
  const float* w_qkv = (const float*)d_in[2];
  const float* temp  = (const float*)d_in[3];
  const float* w_out = (const float*)d_in[4];
  float* out = (float*)d_out;
  char* ws = (char*)d_ws;

  // workspace layout (~86.6 MB):
  ushort_t* xn    = (ushort_t*)ws;                              // 32 MB
  ushort_t* xnT   = (ushort_t*)(ws + (size_t)33554432);         // 512*XSTR*2 = 33,619,968
  float*    S     = (float*)   (ws + (size_t)67174400);         // 8 MB f32
  ushort_t* PT    = (ushort_t*)(ws + (size_t)75563008);         // 8 MB
  ushort_t* MT    = (ushort_t*)(ws + (size_t)83951616);         // 4 MB
  ushort_t* attnT = (ushort_t*)(ws + (size_t)88145920);         // 0.5 MB
  ushort_t* wqkT  = (ushort_t*)(ws + (size_t)88670208);         // 1 MB
  ushort_t* woutT = (ushort_t*)(ws + (size_t)89718784);         // 0.5 MB
  ushort_t* wv    = (ushort_t*)(ws + (size_t)90243072);         // 0.5 MB

  prep_rms_k<<<9600, 256, 0, stream>>>(x, gamma, xn, w_qkv, w_out, wqkT, woutT, wv, S);
  xnt_k<<<4096, 256, 0, stream>>>(xn, xnT);
  syrk_k<<<256, 512, 0, stream>>>(xnT, S);
  pt_k<<<256, 256, 0, stream>>>(wqkT, S, PT);
  gsm_k<<<64, 256, 0, stream>>>(wqkT, PT, temp, attnT);
  atmt_k<<<128, 256, 0, stream>>>(woutT, attnT, wv, MT);
  final_k<<<512, 512, 0, stream>>>(xn, MT, out);
}